// Round 7
// baseline (972.819 us; speedup 1.0000x reference)
//
#include <hip/hip_runtime.h>
#include <hip/hip_bf16.h>

// ---------------------------------------------------------------------------
// GINEdge: 3-layer GIN (sum agg) + per-layer edge MLP scoring.
//   relu([h_s,h_d]@W1+b1)@W2 == relu(P1[s]+P2[d])@W2,
//   P1 = h@W1[:64] + b1, P2 = h@W1[64:]  (per-node projections).
// R6 changes vs R5:
//   - fill writes one int2 (src, eord) per edge (halves scattered stores).
//   - agg fused into the layer's first GEMM (agg_gemm_kernel): kills zb
//     round-trip + 3 launches.
//   - edge scores accumulate into CSR-ordered sc[] (coalesced RMW); one
//     final scatter to original edge order.
//   - scan2 merged into scan3 (NB<=64 partials scanned per-block in-wave).
// Gather payloads (P1/P2, neighbor c) bf16; all accumulation f32.
// ---------------------------------------------------------------------------

#define BN_EPS 1e-5f

static __device__ __forceinline__ float bf2f(ushort u) {
  return __uint_as_float(((unsigned)u) << 16);
}

__global__ __launch_bounds__(256) void hist_kernel(const int* __restrict__ dst,
                                                   int* __restrict__ deg, int E) {
  int i = blockIdx.x * blockDim.x + threadIdx.x;
  int stride = gridDim.x * blockDim.x;
  for (; i < E; i += stride) atomicAdd(&deg[dst[i]], 1);
}

// scan step 1: per-block (1024 elems) exclusive scan + block sum
__global__ __launch_bounds__(256) void scan1_kernel(const int* __restrict__ deg,
                                                    int* __restrict__ rowstart,
                                                    int* __restrict__ partials, int N) {
  __shared__ int wsum[4];
  int tid = threadIdx.x;
  int lane = tid & 63, w = tid >> 6;
  int base = blockIdx.x * 1024 + tid * 4;
  int d0 = 0, d1 = 0, d2 = 0, d3 = 0;
  if (base + 3 < N) {
    int4 v = *reinterpret_cast<const int4*>(deg + base);
    d0 = v.x; d1 = v.y; d2 = v.z; d3 = v.w;
  } else {
    if (base + 0 < N) d0 = deg[base + 0];
    if (base + 1 < N) d1 = deg[base + 1];
    if (base + 2 < N) d2 = deg[base + 2];
  }
  int t0 = d0, t1 = t0 + d1, t2 = t1 + d2, t3 = t2 + d3;
  int tot = t3;
  int inc = tot;
#pragma unroll
  for (int off = 1; off < 64; off <<= 1) {
    int v = __shfl_up(inc, off);
    if (lane >= off) inc += v;
  }
  if (lane == 63) wsum[w] = inc;
  __syncthreads();
  int woff = 0;
  for (int k = 0; k < w; ++k) woff += wsum[k];
  int excl = woff + inc - tot;
  if (base + 0 < N) rowstart[base + 0] = excl;
  if (base + 1 < N) rowstart[base + 1] = excl + t0;
  if (base + 2 < N) rowstart[base + 2] = excl + t1;
  if (base + 3 < N) rowstart[base + 3] = excl + t2;
  if (tid == 255) partials[blockIdx.x] = excl + t3;
}

// scan step 2 (merged): every block wave-scans the <=64 partials to get its
// own offset; adds it; mirrors into cursor.  NB must be <= 64 (N <= 65536).
__global__ __launch_bounds__(256) void scan3_kernel(const int* __restrict__ partials,
                                                    int* __restrict__ rowstart,
                                                    int* __restrict__ cursor,
                                                    int N, int NB, int E) {
  __shared__ int s_off;
  int tid = threadIdx.x;
  if (tid < 64) {
    int v = (tid < NB) ? partials[tid] : 0;
    int inc = v;
#pragma unroll
    for (int off = 1; off < 64; off <<= 1) {
      int t = __shfl_up(inc, off);
      if (tid >= off) inc += t;
    }
    if (tid == (int)blockIdx.x) s_off = inc - v;  // blockIdx.x < NB <= 64
  }
  __syncthreads();
  int off = s_off;
  int base = blockIdx.x * 1024 + tid * 4;
#pragma unroll
  for (int k = 0; k < 4; ++k) {
    int i = base + k;
    if (i < N) {
      int r = rowstart[i] + off;
      rowstart[i] = r;
      cursor[i] = r;
    }
  }
  if (blockIdx.x == 0 && tid == 0) rowstart[N] = E;
}

__global__ __launch_bounds__(256) void fill_kernel(const int* __restrict__ src,
                                                   const int* __restrict__ dst,
                                                   int* __restrict__ cursor,
                                                   int2* __restrict__ epack, int E) {
  int i = blockIdx.x * blockDim.x + threadIdx.x;
  int stride = gridDim.x * blockDim.x;
  for (; i < E; i += stride) {
    int p = atomicAdd(&cursor[dst[i]], 1);
    epack[p] = make_int2(src[i], i);  // (src, original edge id) in one 8B store
  }
}

// z1[n] = b1 + (T(c[n]) + sum_{u->n} T(cb[u])) @ W ; T = id (TR=0) or
// relu-affine (TR=1, deferred bn_out).  Agg staged directly into LDS, then
// 64x64 GEMM.  Optional col sum/sumsq of z1 into stats_out.
template <int TR>
__global__ __launch_bounds__(256) void agg_gemm_kernel(
    const float* __restrict__ c, const ushort* __restrict__ cb,
    const int2* __restrict__ epack, const int* __restrict__ rowstart,
    const float* __restrict__ W, const float* __restrict__ bias,
    const float* __restrict__ stats_tr, const float* __restrict__ g_tr,
    const float* __restrict__ b_tr, float* __restrict__ out,
    float* __restrict__ stats_out, int N) {
  __shared__ float sW[64][64];
  __shared__ float sx[32][64];
  __shared__ float red[2][4][64];
  int tid = threadIdx.x, lane = tid & 63, w = tid >> 6;
  int n0 = blockIdx.x * 32;
#pragma unroll
  for (int r = 0; r < 16; ++r) {
    int idx = r * 256 + tid;
    sW[idx >> 6][idx & 63] = W[idx];
  }
  float sc = 1.f, sh = 0.f;
  if (TR) {
    float invN = 1.0f / (float)N;
    float m = stats_tr[lane] * invN;
    float var = stats_tr[64 + lane] * invN - m * m;
    sc = g_tr[lane] * rsqrtf(var + BN_EPS);
    sh = b_tr[lane] - m * sc;
  }
  // aggregate 8 nodes per wave (8-wide batched neighbor gathers)
  for (int j = 0; j < 8; ++j) {
    int v = n0 + w * 8 + j;
    float acc = 0.f;
    if (v < N) {
      float x0 = c[(size_t)v * 64 + lane];
      acc = TR ? fmaxf(x0 * sc + sh, 0.f) : x0;
      int p = rowstart[v], pe = rowstart[v + 1];
      for (; p + 8 <= pe; p += 8) {
        int u[8];
#pragma unroll
        for (int k = 0; k < 8; ++k) u[k] = epack[p + k].x;
        float x[8];
#pragma unroll
        for (int k = 0; k < 8; ++k) x[k] = bf2f(cb[(size_t)u[k] * 64 + lane]);
#pragma unroll
        for (int k = 0; k < 8; ++k) acc += TR ? fmaxf(x[k] * sc + sh, 0.f) : x[k];
      }
      for (; p < pe; ++p) {
        float x = bf2f(cb[(size_t)epack[p].x * 64 + lane]);
        acc += TR ? fmaxf(x * sc + sh, 0.f) : x;
      }
    }
    sx[w * 8 + j][lane] = acc;
  }
  __syncthreads();
  float o[8];
  float bz = bias[lane];
#pragma unroll
  for (int j = 0; j < 8; ++j) o[j] = bz;
  for (int k = 0; k < 64; ++k) {
    float wv = sW[k][lane];
#pragma unroll
    for (int j = 0; j < 8; ++j) o[j] = fmaf(sx[w * 8 + j][k], wv, o[j]);
  }
  float ps = 0.f, pq = 0.f;
#pragma unroll
  for (int j = 0; j < 8; ++j) {
    int n = n0 + w * 8 + j;
    if (n < N) {
      out[(size_t)n * 64 + lane] = o[j];
      ps += o[j];
      pq += o[j] * o[j];
    }
  }
  if (stats_out) {
    red[0][w][lane] = ps;
    red[1][w][lane] = pq;
    __syncthreads();
    if (w == 0) {
      float s = red[0][0][lane] + red[0][1][lane] + red[0][2][lane] + red[0][3][lane];
      float q = red[1][0][lane] + red[1][1][lane] + red[1][2][lane] + red[1][3][lane];
      atomicAdd(&stats_out[lane], s);
      atomicAdd(&stats_out[64 + lane], q);
    }
  }
}

// out[n][f] = bias[f] + sum_k T(in[n][k]) * W[k][f]
// T = identity, or (if stats_in) relu(bn(x)). Optional col stats of out;
// optional bf16 mirror.
__global__ __launch_bounds__(256) void gemm64_kernel(
    const float* __restrict__ in, const float* __restrict__ W,
    const float* __restrict__ bias, const float* __restrict__ stats_in,
    const float* __restrict__ g_in, const float* __restrict__ b_in,
    float* __restrict__ out, float* __restrict__ stats_out,
    __hip_bfloat16* __restrict__ out_bf, int N) {
  __shared__ float sW[64][64];
  __shared__ float sx[32][64];
  __shared__ float red[2][4][64];
  int tid = threadIdx.x;
  int lane = tid & 63, w = tid >> 6;
  int n0 = blockIdx.x * 32;
#pragma unroll
  for (int r = 0; r < 16; ++r) {
    int idx = r * 256 + tid;
    sW[idx >> 6][idx & 63] = W[idx];
  }
  float sc = 1.f, sh = 0.f;
  if (stats_in) {
    float invN = 1.0f / (float)N;
    float m = stats_in[lane] * invN;
    float var = stats_in[64 + lane] * invN - m * m;
    sc = g_in[lane] * rsqrtf(var + BN_EPS);
    sh = b_in[lane] - m * sc;
  }
#pragma unroll
  for (int r = 0; r < 8; ++r) {
    int idx = r * 256 + tid;  // (idx&63)==lane since 256%64==0
    int n = n0 + (idx >> 6);
    float x = (n < N) ? in[(size_t)n * 64 + lane] : 0.f;
    if (stats_in) x = fmaxf(x * sc + sh, 0.f);
    sx[idx >> 6][lane] = x;
  }
  __syncthreads();
  float acc[8];
  float bz = bias ? bias[lane] : 0.f;
#pragma unroll
  for (int j = 0; j < 8; ++j) acc[j] = bz;
  for (int k = 0; k < 64; ++k) {
    float wv = sW[k][lane];
#pragma unroll
    for (int j = 0; j < 8; ++j) acc[j] = fmaf(sx[w * 8 + j][k], wv, acc[j]);
  }
  float ps = 0.f, pq = 0.f;
#pragma unroll
  for (int j = 0; j < 8; ++j) {
    int n = n0 + w * 8 + j;
    if (n < N) {
      out[(size_t)n * 64 + lane] = acc[j];
      if (out_bf) out_bf[(size_t)n * 64 + lane] = __float2bfloat16(acc[j]);
      ps += acc[j];
      pq += acc[j] * acc[j];
    }
  }
  if (stats_out) {
    red[0][w][lane] = ps;
    red[1][w][lane] = pq;
    __syncthreads();
    if (w == 0) {
      float s = red[0][0][lane] + red[0][1][lane] + red[0][2][lane] + red[0][3][lane];
      float q = red[1][0][lane] + red[1][1][lane] + red[1][2][lane] + red[1][3][lane];
      atomicAdd(&stats_out[lane], s);
      atomicAdd(&stats_out[64 + lane], q);
    }
  }
}

// P1 = T(c) @ W1[0:64] + b1 ; P2 = T(c) @ W1[64:128]  -> bf16
// T = identity or relu-affine (deferred bn_out).
__global__ __launch_bounds__(256) void proj_kernel(
    const float* __restrict__ c, const float* __restrict__ W1,
    const float* __restrict__ b1, const float* __restrict__ stats_in,
    const float* __restrict__ g_in, const float* __restrict__ b_in,
    __hip_bfloat16* __restrict__ P1, __hip_bfloat16* __restrict__ P2, int N) {
  __shared__ float sWa[64][64];
  __shared__ float sWb[64][64];
  __shared__ float sx[32][64];
  int tid = threadIdx.x, lane = tid & 63, w = tid >> 6;
  int n0 = blockIdx.x * 32;
#pragma unroll
  for (int r = 0; r < 16; ++r) {
    int idx = r * 256 + tid;
    sWa[idx >> 6][idx & 63] = W1[idx];
    sWb[idx >> 6][idx & 63] = W1[4096 + idx];
  }
  float sc = 1.f, sh = 0.f;
  if (stats_in) {
    float invN = 1.0f / (float)N;
    float m = stats_in[lane] * invN;
    float var = stats_in[64 + lane] * invN - m * m;
    sc = g_in[lane] * rsqrtf(var + BN_EPS);
    sh = b_in[lane] - m * sc;
  }
#pragma unroll
  for (int r = 0; r < 8; ++r) {
    int idx = r * 256 + tid;
    int n = n0 + (idx >> 6);
    float x = (n < N) ? c[(size_t)n * 64 + lane] : 0.f;
    if (stats_in) x = fmaxf(x * sc + sh, 0.f);
    sx[idx >> 6][lane] = x;
  }
  __syncthreads();
  float a1[8], a2[8];
  float bz = b1[lane];
#pragma unroll
  for (int j = 0; j < 8; ++j) { a1[j] = bz; a2[j] = 0.f; }
  for (int k = 0; k < 64; ++k) {
    float wa = sWa[k][lane];
    float wb = sWb[k][lane];
#pragma unroll
    for (int j = 0; j < 8; ++j) {
      float x = sx[w * 8 + j][k];
      a1[j] = fmaf(x, wa, a1[j]);
      a2[j] = fmaf(x, wb, a2[j]);
    }
  }
#pragma unroll
  for (int j = 0; j < 8; ++j) {
    int n = n0 + w * 8 + j;
    if (n < N) {
      P1[(size_t)n * 64 + lane] = __float2bfloat16(a1[j]);
      P2[(size_t)n * 64 + lane] = __float2bfloat16(a2[j]);
    }
  }
}

// t = relu(bn(in)); col stats of t; bf16 mirror.  (apply_bn stage)
__global__ __launch_bounds__(256) void bnrelu_kernel(
    const float* __restrict__ in, const float* __restrict__ stats_in,
    const float* __restrict__ g_in, const float* __restrict__ b_in,
    float* __restrict__ out, float* __restrict__ stats_out,
    __hip_bfloat16* __restrict__ out_bf, int N) {
  __shared__ float red[2][4][64];
  int tid = threadIdx.x;
  int lane = tid & 63, w = tid >> 6;
  float invN = 1.0f / (float)N;
  float m = stats_in[lane] * invN;
  float var = stats_in[64 + lane] * invN - m * m;
  float sc = g_in[lane] * rsqrtf(var + BN_EPS);
  float sh = b_in[lane] - m * sc;
  float ps = 0.f, pq = 0.f;
  int rows_per_grid = gridDim.x * (blockDim.x >> 6);
  for (int n = blockIdx.x * (blockDim.x >> 6) + w; n < N; n += rows_per_grid) {
    float x = fmaxf(in[(size_t)n * 64 + lane] * sc + sh, 0.f);
    out[(size_t)n * 64 + lane] = x;
    if (out_bf) out_bf[(size_t)n * 64 + lane] = __float2bfloat16(x);
    ps += x;
    pq += x * x;
  }
  if (stats_out) {
    red[0][w][lane] = ps;
    red[1][w][lane] = pq;
    __syncthreads();
    if (w == 0) {
      float s = red[0][0][lane] + red[0][1][lane] + red[0][2][lane] + red[0][3][lane];
      float q = red[1][0][lane] + red[1][1][lane] + red[1][2][lane] + red[1][3][lane];
      atomicAdd(&stats_out[lane], s);
      atomicAdd(&stats_out[64 + lane], q);
    }
  }
}

// CSR (dst-major) edge scoring into CSR-ordered sc[] (coalesced RMW).
// Wave per dst node v; P2[v] in regs; 8 lane-groups score 8 edges/iter,
// gathering only P1[src].  sc[p] (+)= relu(P1[s]+P2[v]) @ W2 + b2.
__global__ __launch_bounds__(256) void edge_score_csr_kernel(
    const ushort* __restrict__ P1, const ushort* __restrict__ P2,
    const int* __restrict__ rowstart, const int2* __restrict__ epack,
    const float* __restrict__ W2, const float* __restrict__ b2,
    float2* __restrict__ sc, int N, int first) {
  int lane = threadIdx.x & 63;
  int v = blockIdx.x * 4 + (threadIdx.x >> 6);
  if (v >= N) return;
  int sub = lane & 7;   // feature octet within the 64
  int grp = lane >> 3;  // edge slot (8 edges in flight per wave)
  float w[16];
  const float4* wp = reinterpret_cast<const float4*>(W2 + sub * 16);
#pragma unroll
  for (int k = 0; k < 4; ++k) {
    float4 t = wp[k];
    w[4 * k + 0] = t.x; w[4 * k + 1] = t.y; w[4 * k + 2] = t.z; w[4 * k + 3] = t.w;
  }
  float bb0 = b2[0], bb1 = b2[1];
  uint4 pb = *reinterpret_cast<const uint4*>(P2 + (size_t)v * 64 + sub * 8);
  unsigned bv[4] = {pb.x, pb.y, pb.z, pb.w};
  int p0 = rowstart[v], p1 = rowstart[v + 1];
  for (int p = p0 + grp; p < p1; p += 8) {
    int s = epack[p].x;
    uint4 pa = *reinterpret_cast<const uint4*>(P1 + (size_t)s * 64 + sub * 8);
    unsigned av[4] = {pa.x, pa.y, pa.z, pa.w};
    float q0 = 0.f, q1 = 0.f;
#pragma unroll
    for (int k = 0; k < 4; ++k) {
      float a_lo = __uint_as_float(av[k] << 16);
      float a_hi = __uint_as_float(av[k] & 0xffff0000u);
      float b_lo = __uint_as_float(bv[k] << 16);
      float b_hi = __uint_as_float(bv[k] & 0xffff0000u);
      float v0 = fmaxf(a_lo + b_lo, 0.f);
      float v1 = fmaxf(a_hi + b_hi, 0.f);
      q0 = fmaf(v0, w[4 * k + 0], fmaf(v1, w[4 * k + 2], q0));
      q1 = fmaf(v0, w[4 * k + 1], fmaf(v1, w[4 * k + 3], q1));
    }
#pragma unroll
    for (int mm = 1; mm < 8; mm <<= 1) {
      q0 += __shfl_xor(q0, mm);
      q1 += __shfl_xor(q1, mm);
    }
    if (sub == 0) {
      float o0 = q0 + bb0, o1 = q1 + bb1;
      if (!first) {
        float2 prev = sc[p];
        o0 += prev.x;
        o1 += prev.y;
      }
      sc[p] = make_float2(o0, o1);
    }
  }
}

// final permute: CSR-ordered scores -> original edge order
__global__ __launch_bounds__(256) void scatter_kernel(const float2* __restrict__ sc,
                                                      const int2* __restrict__ epack,
                                                      float2* __restrict__ out, int E) {
  int i = blockIdx.x * blockDim.x + threadIdx.x;
  int stride = gridDim.x * blockDim.x;
  for (; i < E; i += stride) out[epack[i].y] = sc[i];
}

extern "C" void kernel_launch(void* const* d_in, const int* in_sizes, int n_in,
                              void* d_out, int out_size, void* d_ws, size_t ws_size,
                              hipStream_t stream) {
  const float* h          = (const float*)d_in[0];
  const int*   src        = (const int*)d_in[1];
  const int*   dst        = (const int*)d_in[2];
  const float* emb_W      = (const float*)d_in[3];
  const float* emb_b      = (const float*)d_in[4];
  const float* mlp_W1     = (const float*)d_in[5];
  const float* mlp_b1     = (const float*)d_in[6];
  const float* mlp_bn_g   = (const float*)d_in[7];
  const float* mlp_bn_b   = (const float*)d_in[8];
  const float* mlp_W2     = (const float*)d_in[9];
  const float* mlp_b2     = (const float*)d_in[10];
  const float* apply_bn_g = (const float*)d_in[11];
  const float* apply_bn_b = (const float*)d_in[12];
  const float* out_bn_g   = (const float*)d_in[13];
  const float* out_bn_b   = (const float*)d_in[14];
  const float* pred_W1    = (const float*)d_in[15];
  const float* pred_b1    = (const float*)d_in[16];
  const float* pred_W2    = (const float*)d_in[17];
  const float* pred_b2    = (const float*)d_in[18];

  const int N = in_sizes[0] / 64;
  const int E = in_sizes[1];
  const size_t NF = (size_t)N * 64;
  const int NB1 = (N + 1023) / 1024;  // scan3 requires NB1 <= 64 (N <= 65536)

  float* ws = (float*)d_ws;
  float* c  = ws;             // current node features (f32), pre-bn_out
  float* z1 = c + NF;
  float* z2 = z1 + NF;
  __hip_bfloat16* cb = (__hip_bfloat16*)(z2 + NF);  // bf16 mirror of c
  __hip_bfloat16* P1 = cb + NF;
  __hip_bfloat16* P2 = P1 + NF;
  int2*   epack  = (int2*)(P2 + NF);          // (src, orig edge id) per CSR slot
  float2* scbuf  = (float2*)(epack + E);      // CSR-ordered accumulated scores
  int* rowstart  = (int*)(scbuf + E);         // N+1 (padded)
  int* cursor    = rowstart + (N + 64);
  int* partials  = cursor + (N + 64);         // 64
  int* deg       = partials + 64;
  float* stats   = (float*)(deg + (N + 64));  // 9 slots x [sum(64), sumsq(64)]

  size_t need = (size_t)((char*)(stats + 9 * 128) - (char*)d_ws);
  if (need > ws_size) return;

  // zero deg + stats in one async memset (graph-capture safe)
  hipMemsetAsync(deg, 0, ((size_t)(N + 64) + 9 * 128) * sizeof(int), stream);

  const int gemmBlocks = (N + 31) / 32;
  const int nodeBlocks = (N + 3) / 4;

  // embedding: c = h @ emb_W + emb_b  (+ bf16 mirror)
  gemm64_kernel<<<gemmBlocks, 256, 0, stream>>>(h, emb_W, emb_b, nullptr, nullptr,
                                                nullptr, c, nullptr, cb, N);
  // CSR build (by dst), packed (src, edge-id)
  hist_kernel<<<1024, 256, 0, stream>>>(dst, deg, E);
  scan1_kernel<<<NB1, 256, 0, stream>>>(deg, rowstart, partials, N);
  scan3_kernel<<<NB1, 256, 0, stream>>>(partials, rowstart, cursor, N, NB1, E);
  fill_kernel<<<1024, 256, 0, stream>>>(src, dst, cursor, epack, E);

  // edge rep 0 scoring (identity transform)
  proj_kernel<<<gemmBlocks, 256, 0, stream>>>(c, pred_W1, pred_b1, nullptr, nullptr,
                                              nullptr, P1, P2, N);
  edge_score_csr_kernel<<<nodeBlocks, 256, 0, stream>>>(
      (const ushort*)P1, (const ushort*)P2, rowstart, epack, pred_W2, pred_b2,
      scbuf, N, 1);

  for (int i = 0; i < 3; ++i) {
    float* st1 = stats + (size_t)(3 * i + 0) * 128;
    float* st2 = stats + (size_t)(3 * i + 1) * 128;
    float* st3 = stats + (size_t)(3 * i + 2) * 128;
    const float* stP = (i == 0) ? nullptr : stats + (size_t)(3 * (i - 1) + 2) * 128;
    const float* gP  = (i == 0) ? nullptr : out_bn_g + (i - 1) * 64;
    const float* bP  = (i == 0) ? nullptr : out_bn_b + (i - 1) * 64;

    // z1 = (T(c) + segment_sum(T(c)[src], dst)) @ W1 + b1  (+ stats)
    if (i == 0)
      agg_gemm_kernel<0><<<gemmBlocks, 256, 0, stream>>>(
          c, (const ushort*)cb, epack, rowstart, mlp_W1 + (size_t)i * 4096,
          mlp_b1 + i * 64, nullptr, nullptr, nullptr, z1, st1, N);
    else
      agg_gemm_kernel<1><<<gemmBlocks, 256, 0, stream>>>(
          c, (const ushort*)cb, epack, rowstart, mlp_W1 + (size_t)i * 4096,
          mlp_b1 + i * 64, stP, gP, bP, z1, st1, N);
    // z2 = relu(bn_mlp(z1)) @ W2 + b2  (+ stats)
    gemm64_kernel<<<gemmBlocks, 256, 0, stream>>>(z1, mlp_W2 + (size_t)i * 4096,
                                                  mlp_b2 + i * 64, st1,
                                                  mlp_bn_g + i * 64, mlp_bn_b + i * 64,
                                                  z2, st2, nullptr, N);
    // c = relu(bn_apply(z2))  (+ stats st3, bf16 mirror); bn_out deferred
    bnrelu_kernel<<<784, 256, 0, stream>>>(z2, st2, apply_bn_g + i * 64,
                                           apply_bn_b + i * 64, c, st3, cb, N);
    // edge rep (i+1): proj applies deferred bn_out[i] via st3
    proj_kernel<<<gemmBlocks, 256, 0, stream>>>(c, pred_W1 + (size_t)(i + 1) * 8192,
                                                pred_b1 + (i + 1) * 64, st3,
                                                out_bn_g + i * 64, out_bn_b + i * 64,
                                                P1, P2, N);
    edge_score_csr_kernel<<<nodeBlocks, 256, 0, stream>>>(
        (const ushort*)P1, (const ushort*)P2, rowstart, epack,
        pred_W2 + (i + 1) * 128, pred_b2 + (i + 1) * 2, scbuf, N, 0);
  }

  // CSR order -> original edge order
  scatter_kernel<<<2048, 256, 0, stream>>>(scbuf, epack, (float2*)d_out, E);
}

// Round 8
// 926.208 us; speedup vs baseline: 1.0503x; 1.0503x over previous
//
#include <hip/hip_runtime.h>
#include <hip/hip_bf16.h>

// ---------------------------------------------------------------------------
// GINEdge: 3-layer GIN (sum agg) + per-layer edge MLP scoring.
//   relu([h_s,h_d]@W1+b1)@W2 == relu(P1[s]+P2[d])@W2,
//   P1 = h@W1[:64] + b1, P2 = h@W1[64:]  (per-node projections).
// R8 changes vs R7:
//   - REVERT agg+GEMM fusion (it serialized the latency-bound gather: 30% occ).
//   - FUSE the two per-layer edge walks instead: score(rep i) + agg(layer i)
//     in ONE wave-per-node kernel over a packed record G[n]=[P1row|cbrow]
//     (256B contiguous). 16 lanes/edge: lanes 0-7 score, lanes 8-15 agg.
//   - zb round-trip returns (cheap, streaming); z2 aliases zb to fit ws.
// Gather payloads bf16; all accumulation f32.
// ---------------------------------------------------------------------------

#define BN_EPS 1e-5f

static __device__ __forceinline__ float bf2f_lo(unsigned u) {
  return __uint_as_float(u << 16);
}
static __device__ __forceinline__ float bf2f_hi(unsigned u) {
  return __uint_as_float(u & 0xffff0000u);
}

__global__ __launch_bounds__(256) void hist_kernel(const int* __restrict__ dst,
                                                   int* __restrict__ deg, int E) {
  int i = blockIdx.x * blockDim.x + threadIdx.x;
  int stride = gridDim.x * blockDim.x;
  for (; i < E; i += stride) atomicAdd(&deg[dst[i]], 1);
}

// scan step 1: per-block (1024 elems) exclusive scan + block sum
__global__ __launch_bounds__(256) void scan1_kernel(const int* __restrict__ deg,
                                                    int* __restrict__ rowstart,
                                                    int* __restrict__ partials, int N) {
  __shared__ int wsum[4];
  int tid = threadIdx.x;
  int lane = tid & 63, w = tid >> 6;
  int base = blockIdx.x * 1024 + tid * 4;
  int d0 = 0, d1 = 0, d2 = 0, d3 = 0;
  if (base + 3 < N) {
    int4 v = *reinterpret_cast<const int4*>(deg + base);
    d0 = v.x; d1 = v.y; d2 = v.z; d3 = v.w;
  } else {
    if (base + 0 < N) d0 = deg[base + 0];
    if (base + 1 < N) d1 = deg[base + 1];
    if (base + 2 < N) d2 = deg[base + 2];
  }
  int t0 = d0, t1 = t0 + d1, t2 = t1 + d2, t3 = t2 + d3;
  int tot = t3;
  int inc = tot;
#pragma unroll
  for (int off = 1; off < 64; off <<= 1) {
    int v = __shfl_up(inc, off);
    if (lane >= off) inc += v;
  }
  if (lane == 63) wsum[w] = inc;
  __syncthreads();
  int woff = 0;
  for (int k = 0; k < w; ++k) woff += wsum[k];
  int excl = woff + inc - tot;
  if (base + 0 < N) rowstart[base + 0] = excl;
  if (base + 1 < N) rowstart[base + 1] = excl + t0;
  if (base + 2 < N) rowstart[base + 2] = excl + t1;
  if (base + 3 < N) rowstart[base + 3] = excl + t2;
  if (tid == 255) partials[blockIdx.x] = excl + t3;
}

// scan step 2 (merged): every block wave-scans the <=64 partials; adds its
// offset; mirrors into cursor.  Requires NB <= 64 (N <= 65536).
__global__ __launch_bounds__(256) void scan3_kernel(const int* __restrict__ partials,
                                                    int* __restrict__ rowstart,
                                                    int* __restrict__ cursor,
                                                    int N, int NB, int E) {
  __shared__ int s_off;
  int tid = threadIdx.x;
  if (tid < 64) {
    int v = (tid < NB) ? partials[tid] : 0;
    int inc = v;
#pragma unroll
    for (int off = 1; off < 64; off <<= 1) {
      int t = __shfl_up(inc, off);
      if (tid >= off) inc += t;
    }
    if (tid == (int)blockIdx.x) s_off = inc - v;
  }
  __syncthreads();
  int off = s_off;
  int base = blockIdx.x * 1024 + tid * 4;
#pragma unroll
  for (int k = 0; k < 4; ++k) {
    int i = base + k;
    if (i < N) {
      int r = rowstart[i] + off;
      rowstart[i] = r;
      cursor[i] = r;
    }
  }
  if (blockIdx.x == 0 && tid == 0) rowstart[N] = E;
}

__global__ __launch_bounds__(256) void fill_kernel(const int* __restrict__ src,
                                                   const int* __restrict__ dst,
                                                   int* __restrict__ cursor,
                                                   int2* __restrict__ epack, int E) {
  int i = blockIdx.x * blockDim.x + threadIdx.x;
  int stride = gridDim.x * blockDim.x;
  for (; i < E; i += stride) {
    int p = atomicAdd(&cursor[dst[i]], 1);
    epack[p] = make_int2(src[i], i);  // (src, original edge id) one 8B store
  }
}

// out[n][f] = bias[f] + sum_k in[n][k]*W[k][f]; col stats optional; optional
// bf16 mirror into packed G (row stride 128 ushorts), base = G + 64.
__global__ __launch_bounds__(256) void gemm64_kernel(
    const float* __restrict__ in, const float* __restrict__ W,
    const float* __restrict__ bias, const float* __restrict__ stats_in,
    const float* __restrict__ g_in, const float* __restrict__ b_in,
    float* __restrict__ out, float* __restrict__ stats_out,
    ushort* __restrict__ out_g, int N) {
  __shared__ float sW[64][64];
  __shared__ float sx[32][64];
  __shared__ float red[2][4][64];
  int tid = threadIdx.x;
  int lane = tid & 63, w = tid >> 6;
  int n0 = blockIdx.x * 32;
#pragma unroll
  for (int r = 0; r < 16; ++r) {
    int idx = r * 256 + tid;
    sW[idx >> 6][idx & 63] = W[idx];
  }
  float sc = 1.f, sh = 0.f;
  if (stats_in) {
    float invN = 1.0f / (float)N;
    float m = stats_in[lane] * invN;
    float var = stats_in[64 + lane] * invN - m * m;
    sc = g_in[lane] * rsqrtf(var + BN_EPS);
    sh = b_in[lane] - m * sc;
  }
#pragma unroll
  for (int r = 0; r < 8; ++r) {
    int idx = r * 256 + tid;  // (idx&63)==lane since 256%64==0
    int n = n0 + (idx >> 6);
    float x = (n < N) ? in[(size_t)n * 64 + lane] : 0.f;
    if (stats_in) x = fmaxf(x * sc + sh, 0.f);
    sx[idx >> 6][lane] = x;
  }
  __syncthreads();
  float acc[8];
  float bz = bias ? bias[lane] : 0.f;
#pragma unroll
  for (int j = 0; j < 8; ++j) acc[j] = bz;
  for (int k = 0; k < 64; ++k) {
    float wv = sW[k][lane];
#pragma unroll
    for (int j = 0; j < 8; ++j) acc[j] = fmaf(sx[w * 8 + j][k], wv, acc[j]);
  }
  float ps = 0.f, pq = 0.f;
#pragma unroll
  for (int j = 0; j < 8; ++j) {
    int n = n0 + w * 8 + j;
    if (n < N) {
      out[(size_t)n * 64 + lane] = acc[j];
      if (out_g) {
        __hip_bfloat16 b = __float2bfloat16(acc[j]);
        out_g[(size_t)n * 128 + lane] = *reinterpret_cast<ushort*>(&b);
      }
      ps += acc[j];
      pq += acc[j] * acc[j];
    }
  }
  if (stats_out) {
    red[0][w][lane] = ps;
    red[1][w][lane] = pq;
    __syncthreads();
    if (w == 0) {
      float s = red[0][0][lane] + red[0][1][lane] + red[0][2][lane] + red[0][3][lane];
      float q = red[1][0][lane] + red[1][1][lane] + red[1][2][lane] + red[1][3][lane];
      atomicAdd(&stats_out[lane], s);
      atomicAdd(&stats_out[64 + lane], q);
    }
  }
}

// P1 = T(c) @ W1[0:64] + b1 -> packed G (stride 128, offset 0);
// P2 = T(c) @ W1[64:128]    -> separate bf16 [N][64].
// T = identity or relu-affine (deferred bn_out via stats_in).
__global__ __launch_bounds__(256) void proj_kernel(
    const float* __restrict__ c, const float* __restrict__ W1,
    const float* __restrict__ b1, const float* __restrict__ stats_in,
    const float* __restrict__ g_in, const float* __restrict__ b_in,
    ushort* __restrict__ G, ushort* __restrict__ P2, int N) {
  __shared__ float sWa[64][64];
  __shared__ float sWb[64][64];
  __shared__ float sx[32][64];
  int tid = threadIdx.x, lane = tid & 63, w = tid >> 6;
  int n0 = blockIdx.x * 32;
#pragma unroll
  for (int r = 0; r < 16; ++r) {
    int idx = r * 256 + tid;
    sWa[idx >> 6][idx & 63] = W1[idx];
    sWb[idx >> 6][idx & 63] = W1[4096 + idx];
  }
  float sc = 1.f, sh = 0.f;
  if (stats_in) {
    float invN = 1.0f / (float)N;
    float m = stats_in[lane] * invN;
    float var = stats_in[64 + lane] * invN - m * m;
    sc = g_in[lane] * rsqrtf(var + BN_EPS);
    sh = b_in[lane] - m * sc;
  }
#pragma unroll
  for (int r = 0; r < 8; ++r) {
    int idx = r * 256 + tid;
    int n = n0 + (idx >> 6);
    float x = (n < N) ? c[(size_t)n * 64 + lane] : 0.f;
    if (stats_in) x = fmaxf(x * sc + sh, 0.f);
    sx[idx >> 6][lane] = x;
  }
  __syncthreads();
  float a1[8], a2[8];
  float bz = b1[lane];
#pragma unroll
  for (int j = 0; j < 8; ++j) { a1[j] = bz; a2[j] = 0.f; }
  for (int k = 0; k < 64; ++k) {
    float wa = sWa[k][lane];
    float wb = sWb[k][lane];
#pragma unroll
    for (int j = 0; j < 8; ++j) {
      float x = sx[w * 8 + j][k];
      a1[j] = fmaf(x, wa, a1[j]);
      a2[j] = fmaf(x, wb, a2[j]);
    }
  }
#pragma unroll
  for (int j = 0; j < 8; ++j) {
    int n = n0 + w * 8 + j;
    if (n < N) {
      __hip_bfloat16 b1v = __float2bfloat16(a1[j]);
      __hip_bfloat16 b2v = __float2bfloat16(a2[j]);
      G[(size_t)n * 128 + lane] = *reinterpret_cast<ushort*>(&b1v);
      P2[(size_t)n * 64 + lane] = *reinterpret_cast<ushort*>(&b2v);
    }
  }
}

// c = relu(bn(in)); col stats of c; bf16 mirror into packed G (offset 64).
__global__ __launch_bounds__(256) void bnrelu_kernel(
    const float* __restrict__ in, const float* __restrict__ stats_in,
    const float* __restrict__ g_in, const float* __restrict__ b_in,
    float* __restrict__ out, float* __restrict__ stats_out,
    ushort* __restrict__ out_g, int N) {
  __shared__ float red[2][4][64];
  int tid = threadIdx.x;
  int lane = tid & 63, w = tid >> 6;
  float invN = 1.0f / (float)N;
  float m = stats_in[lane] * invN;
  float var = stats_in[64 + lane] * invN - m * m;
  float sc = g_in[lane] * rsqrtf(var + BN_EPS);
  float sh = b_in[lane] - m * sc;
  float ps = 0.f, pq = 0.f;
  int rows_per_grid = gridDim.x * (blockDim.x >> 6);
  for (int n = blockIdx.x * (blockDim.x >> 6) + w; n < N; n += rows_per_grid) {
    float x = fmaxf(in[(size_t)n * 64 + lane] * sc + sh, 0.f);
    out[(size_t)n * 64 + lane] = x;
    __hip_bfloat16 b = __float2bfloat16(x);
    out_g[(size_t)n * 128 + lane] = *reinterpret_cast<ushort*>(&b);
    ps += x;
    pq += x * x;
  }
  if (stats_out) {
    red[0][w][lane] = ps;
    red[1][w][lane] = pq;
    __syncthreads();
    if (w == 0) {
      float s = red[0][0][lane] + red[0][1][lane] + red[0][2][lane] + red[0][3][lane];
      float q = red[1][0][lane] + red[1][1][lane] + red[1][2][lane] + red[1][3][lane];
      atomicAdd(&stats_out[lane], s);
      atomicAdd(&stats_out[64 + lane], q);
    }
  }
}

// FUSED per-layer edge walk: wave per dst node v; 4 groups x 16 lanes.
// Each group processes one edge per iter, loading the packed 256B record
// G[s] = [P1 row | cb row]:
//   lanes g16<8 : score  sc[p] (+)= relu(P1[s]+P2[v]) @ W2 + b2
//   lanes g16>=8: agg    acc += T(cb[s])   (T = relu-affine if TR)
// Epilogue: zb[v] = T(c[v]) + cross-group-reduced acc.
template <int TR>
__global__ __launch_bounds__(256) void score_agg_kernel(
    const ushort* __restrict__ G, const ushort* __restrict__ P2,
    const float* __restrict__ c, const int* __restrict__ rowstart,
    const int2* __restrict__ epack, const float* __restrict__ W2,
    const float* __restrict__ b2, const float* __restrict__ stats_tr,
    const float* __restrict__ g_tr, const float* __restrict__ b_tr,
    float2* __restrict__ sc, float* __restrict__ zb, int N, int first) {
  int lane = threadIdx.x & 63;
  int v = blockIdx.x * 4 + (threadIdx.x >> 6);
  if (v >= N) return;
  int grp = lane >> 4;  // 0..3 : edge slot
  int g16 = lane & 15;  // role within group
  int sub = g16 & 7;
  // score constants (lanes g16<8 use them)
  float w[16];
  {
    const float4* wp = reinterpret_cast<const float4*>(W2 + sub * 16);
#pragma unroll
    for (int k = 0; k < 4; ++k) {
      float4 t = wp[k];
      w[4 * k + 0] = t.x; w[4 * k + 1] = t.y; w[4 * k + 2] = t.z; w[4 * k + 3] = t.w;
    }
  }
  float bb0 = b2[0], bb1 = b2[1];
  uint4 pb = *reinterpret_cast<const uint4*>(P2 + (size_t)v * 64 + sub * 8);
  unsigned bv[4] = {pb.x, pb.y, pb.z, pb.w};
  // agg affine constants (lanes g16>=8 use them; also epilogue)
  float scv[8], shv[8];
  if (TR) {
    float invN = 1.0f / (float)N;
#pragma unroll
    for (int k = 0; k < 8; ++k) {
      int f = sub * 8 + k;
      float m = stats_tr[f] * invN;
      float var = stats_tr[64 + f] * invN - m * m;
      scv[k] = g_tr[f] * rsqrtf(var + BN_EPS);
      shv[k] = b_tr[f] - m * scv[k];
    }
  }
  float acc[8];
#pragma unroll
  for (int k = 0; k < 8; ++k) acc[k] = 0.f;

  int p0 = rowstart[v], p1 = rowstart[v + 1];
  for (int p = p0 + grp; p < p1; p += 4) {
    int s = epack[p].x;
    uint4 row = *reinterpret_cast<const uint4*>(G + (size_t)s * 128 + g16 * 8);
    unsigned rv[4] = {row.x, row.y, row.z, row.w};
    float q0 = 0.f, q1 = 0.f;
    if (g16 < 8) {
#pragma unroll
      for (int k = 0; k < 4; ++k) {
        float v0 = fmaxf(bf2f_lo(rv[k]) + bf2f_lo(bv[k]), 0.f);
        float v1 = fmaxf(bf2f_hi(rv[k]) + bf2f_hi(bv[k]), 0.f);
        q0 = fmaf(v0, w[4 * k + 0], fmaf(v1, w[4 * k + 2], q0));
        q1 = fmaf(v0, w[4 * k + 1], fmaf(v1, w[4 * k + 3], q1));
      }
    } else {
#pragma unroll
      for (int k = 0; k < 4; ++k) {
        float x0 = bf2f_lo(rv[k]);
        float x1 = bf2f_hi(rv[k]);
        if (TR) {
          x0 = fmaxf(x0 * scv[2 * k] + shv[2 * k], 0.f);
          x1 = fmaxf(x1 * scv[2 * k + 1] + shv[2 * k + 1], 0.f);
        }
        acc[2 * k] += x0;
        acc[2 * k + 1] += x1;
      }
    }
    // reduce score over the group's 8 score lanes (masks stay in-half)
#pragma unroll
    for (int mm = 1; mm < 8; mm <<= 1) {
      q0 += __shfl_xor(q0, mm);
      q1 += __shfl_xor(q1, mm);
    }
    if (g16 == 0) {
      float o0 = q0 + bb0, o1 = q1 + bb1;
      if (!first) {
        float2 prev = sc[p];
        o0 += prev.x;
        o1 += prev.y;
      }
      sc[p] = make_float2(o0, o1);
    }
  }
  // cross-group reduction of agg partials (lanes same g16 across groups)
#pragma unroll
  for (int k = 0; k < 8; ++k) {
    acc[k] += __shfl_xor(acc[k], 16);
    acc[k] += __shfl_xor(acc[k], 32);
  }
  if (grp == 0 && g16 >= 8) {
    const float* cv = c + (size_t)v * 64 + sub * 8;
    float4 c0 = *reinterpret_cast<const float4*>(cv);
    float4 c1 = *reinterpret_cast<const float4*>(cv + 4);
    float cf[8] = {c0.x, c0.y, c0.z, c0.w, c1.x, c1.y, c1.z, c1.w};
    float ov[8];
#pragma unroll
    for (int k = 0; k < 8; ++k) {
      float x = cf[k];
      if (TR) x = fmaxf(x * scv[k] + shv[k], 0.f);
      ov[k] = acc[k] + x;
    }
    float* zp = zb + (size_t)v * 64 + sub * 8;
    *reinterpret_cast<float4*>(zp) = make_float4(ov[0], ov[1], ov[2], ov[3]);
    *reinterpret_cast<float4*>(zp + 4) = make_float4(ov[4], ov[5], ov[6], ov[7]);
  }
}

// score-only CSR walk (last edge rep): 8 lanes/edge, P1 read from packed G.
__global__ __launch_bounds__(256) void edge_score_csr_kernel(
    const ushort* __restrict__ G, const ushort* __restrict__ P2,
    const int* __restrict__ rowstart, const int2* __restrict__ epack,
    const float* __restrict__ W2, const float* __restrict__ b2,
    float2* __restrict__ sc, int N, int first) {
  int lane = threadIdx.x & 63;
  int v = blockIdx.x * 4 + (threadIdx.x >> 6);
  if (v >= N) return;
  int sub = lane & 7;
  int grp = lane >> 3;
  float w[16];
  const float4* wp = reinterpret_cast<const float4*>(W2 + sub * 16);
#pragma unroll
  for (int k = 0; k < 4; ++k) {
    float4 t = wp[k];
    w[4 * k + 0] = t.x; w[4 * k + 1] = t.y; w[4 * k + 2] = t.z; w[4 * k + 3] = t.w;
  }
  float bb0 = b2[0], bb1 = b2[1];
  uint4 pb = *reinterpret_cast<const uint4*>(P2 + (size_t)v * 64 + sub * 8);
  unsigned bv[4] = {pb.x, pb.y, pb.z, pb.w};
  int p0 = rowstart[v], p1 = rowstart[v + 1];
  for (int p = p0 + grp; p < p1; p += 8) {
    int s = epack[p].x;
    uint4 pa = *reinterpret_cast<const uint4*>(G + (size_t)s * 128 + sub * 8);
    unsigned av[4] = {pa.x, pa.y, pa.z, pa.w};
    float q0 = 0.f, q1 = 0.f;
#pragma unroll
    for (int k = 0; k < 4; ++k) {
      float v0 = fmaxf(bf2f_lo(av[k]) + bf2f_lo(bv[k]), 0.f);
      float v1 = fmaxf(bf2f_hi(av[k]) + bf2f_hi(bv[k]), 0.f);
      q0 = fmaf(v0, w[4 * k + 0], fmaf(v1, w[4 * k + 2], q0));
      q1 = fmaf(v0, w[4 * k + 1], fmaf(v1, w[4 * k + 3], q1));
    }
#pragma unroll
    for (int mm = 1; mm < 8; mm <<= 1) {
      q0 += __shfl_xor(q0, mm);
      q1 += __shfl_xor(q1, mm);
    }
    if (sub == 0) {
      float o0 = q0 + bb0, o1 = q1 + bb1;
      if (!first) {
        float2 prev = sc[p];
        o0 += prev.x;
        o1 += prev.y;
      }
      sc[p] = make_float2(o0, o1);
    }
  }
}

// final permute: CSR-ordered scores -> original edge order
__global__ __launch_bounds__(256) void scatter_kernel(const float2* __restrict__ sc,
                                                      const int2* __restrict__ epack,
                                                      float2* __restrict__ out, int E) {
  int i = blockIdx.x * blockDim.x + threadIdx.x;
  int stride = gridDim.x * blockDim.x;
  for (; i < E; i += stride) out[epack[i].y] = sc[i];
}

extern "C" void kernel_launch(void* const* d_in, const int* in_sizes, int n_in,
                              void* d_out, int out_size, void* d_ws, size_t ws_size,
                              hipStream_t stream) {
  const float* h          = (const float*)d_in[0];
  const int*   src        = (const int*)d_in[1];
  const int*   dst        = (const int*)d_in[2];
  const float* emb_W      = (const float*)d_in[3];
  const float* emb_b      = (const float*)d_in[4];
  const float* mlp_W1     = (const float*)d_in[5];
  const float* mlp_b1     = (const float*)d_in[6];
  const float* mlp_bn_g   = (const float*)d_in[7];
  const float* mlp_bn_b   = (const float*)d_in[8];
  const float* mlp_W2     = (const float*)d_in[9];
  const float* mlp_b2     = (const float*)d_in[10];
  const float* apply_bn_g = (const float*)d_in[11];
  const float* apply_bn_b = (const float*)d_in[12];
  const float* out_bn_g   = (const float*)d_in[13];
  const float* out_bn_b   = (const float*)d_in[14];
  const float* pred_W1    = (const float*)d_in[15];
  const float* pred_b1    = (const float*)d_in[16];
  const float* pred_W2    = (const float*)d_in[17];
  const float* pred_b2    = (const float*)d_in[18];

  const int N = in_sizes[0] / 64;
  const int E = in_sizes[1];
  const size_t NF = (size_t)N * 64;
  const int NB1 = (N + 1023) / 1024;  // scan3 requires NB1 <= 64 (N <= 65536)

  float* ws = (float*)d_ws;
  float* c   = ws;            // current node features (f32), pre-bn_out
  float* z1  = c + NF;
  float* zb  = z1 + NF;       // agg output; ALSO reused as z2 (disjoint lifetime)
  ushort* G  = (ushort*)(zb + NF);  // packed [N][128]: [0..63]=P1, [64..127]=cb
  ushort* P2 = G + (size_t)N * 128;
  int2*   epack = (int2*)(P2 + NF); // (src, orig edge id) per CSR slot
  float2* scbuf = (float2*)(epack + E);
  int* rowstart = (int*)(scbuf + E);          // N+1 (padded)
  int* cursor   = rowstart + (N + 64);
  int* partials = cursor + (N + 64);          // 64
  int* deg      = partials + 64;
  float* stats  = (float*)(deg + (N + 64));   // 9 slots x [sum(64), sumsq(64)]

  size_t need = (size_t)((char*)(stats + 9 * 128) - (char*)d_ws);
  if (need > ws_size) return;

  hipMemsetAsync(deg, 0, ((size_t)(N + 64) + 9 * 128) * sizeof(int), stream);

  const int gemmBlocks = (N + 31) / 32;
  const int nodeBlocks = (N + 3) / 4;

  // embedding: c = h @ emb_W + emb_b  (+ cb into packed G)
  gemm64_kernel<<<gemmBlocks, 256, 0, stream>>>(h, emb_W, emb_b, nullptr, nullptr,
                                                nullptr, c, nullptr, G + 64, N);
  // CSR build (by dst)
  hist_kernel<<<1024, 256, 0, stream>>>(dst, deg, E);
  scan1_kernel<<<NB1, 256, 0, stream>>>(deg, rowstart, partials, N);
  scan3_kernel<<<NB1, 256, 0, stream>>>(partials, rowstart, cursor, N, NB1, E);
  fill_kernel<<<1024, 256, 0, stream>>>(src, dst, cursor, epack, E);

  // rep 0: proj (identity) then fused score0 + agg(layer0)
  proj_kernel<<<gemmBlocks, 256, 0, stream>>>(c, pred_W1, pred_b1, nullptr, nullptr,
                                              nullptr, G, P2, N);
  score_agg_kernel<0><<<nodeBlocks, 256, 0, stream>>>(
      G, P2, c, rowstart, epack, pred_W2, pred_b2, nullptr, nullptr, nullptr,
      scbuf, zb, N, 1);

  for (int i = 0; i < 3; ++i) {
    float* st1 = stats + (size_t)(3 * i + 0) * 128;
    float* st2 = stats + (size_t)(3 * i + 1) * 128;
    float* st3 = stats + (size_t)(3 * i + 2) * 128;

    // z1 = zb @ W1 + b1  (+ stats st1)
    gemm64_kernel<<<gemmBlocks, 256, 0, stream>>>(zb, mlp_W1 + (size_t)i * 4096,
                                                  mlp_b1 + i * 64, nullptr, nullptr,
                                                  nullptr, z1, st1, nullptr, N);
    // z2(=zb) = relu(bn_mlp(z1)) @ W2 + b2  (+ stats st2)
    gemm64_kernel<<<gemmBlocks, 256, 0, stream>>>(z1, mlp_W2 + (size_t)i * 4096,
                                                  mlp_b2 + i * 64, st1,
                                                  mlp_bn_g + i * 64, mlp_bn_b + i * 64,
                                                  zb, st2, nullptr, N);
    // c = relu(bn_apply(z2))  (+ stats st3, cb into packed G); bn_out deferred
    bnrelu_kernel<<<784, 256, 0, stream>>>(zb, st2, apply_bn_g + i * 64,
                                           apply_bn_b + i * 64, c, st3, G + 64, N);
    // proj rep i+1 (applies deferred bn_out[i] via st3)
    proj_kernel<<<gemmBlocks, 256, 0, stream>>>(c, pred_W1 + (size_t)(i + 1) * 8192,
                                                pred_b1 + (i + 1) * 64, st3,
                                                out_bn_g + i * 64, out_bn_b + i * 64,
                                                G, P2, N);
    if (i < 2) {
      // fused: score rep i+1 + agg for layer i+1 (affine T via st3/out_bn)
      score_agg_kernel<1><<<nodeBlocks, 256, 0, stream>>>(
          G, P2, c, rowstart, epack, pred_W2 + (i + 1) * 128,
          pred_b2 + (i + 1) * 2, st3, out_bn_g + i * 64, out_bn_b + i * 64,
          scbuf, zb, N, 0);
    } else {
      // last rep: score only
      edge_score_csr_kernel<<<nodeBlocks, 256, 0, stream>>>(
          G, P2, rowstart, epack, pred_W2 + (i + 1) * 128,
          pred_b2 + (i + 1) * 2, scbuf, N, 0);
    }
  }

  // CSR order -> original edge order
  scatter_kernel<<<2048, 256, 0, stream>>>(scbuf, epack, (float2*)d_out, E);
}